// Round 8
// baseline (220.298 us; speedup 1.0000x reference)
//
#include <hip/hip_runtime.h>
#include <hip/hip_bf16.h>

#define E_DIM 1024
#define T_LEN 2048
#define S_LEN 2048
#define B_SZ  8
#define SCALE 0.125f

typedef short short8 __attribute__((ext_vector_type(8)));
typedef float f32x4 __attribute__((ext_vector_type(4)));

// Raw barrier: deliberately NOT a compiler memory fence — lets hipcc hoist
// next-phase ds_reads into the MFMA region (software pipelining).  All
// cross-wave ordering is enforced by the explicit waitcnt asm below.
#define BARRIER() __builtin_amdgcn_s_barrier()

static __device__ __forceinline__ unsigned short f2bf(float f) {
  __hip_bfloat16 h = __float2bfloat16(f);
  return __builtin_bit_cast(unsigned short, h);
}

// ---------------------------------------------------------------------------
// Kernel 1: cast q (scaled), k, W to bf16 ([B][T|S][E]) and zero denom[B*T].
// ---------------------------------------------------------------------------
__global__ __launch_bounds__(256) void prep_kernel(
    const float* __restrict__ q1, const float* __restrict__ kin,
    const float* __restrict__ W,
    unsigned short* __restrict__ qbf, unsigned short* __restrict__ kbf,
    unsigned short* __restrict__ wbf, float* __restrict__ denom) {
  const int QV = B_SZ * T_LEN * (E_DIM / 4);  // float4 count for q (and k)
  const int WV = (E_DIM * E_DIM) / 4;
  const int DN = (B_SZ * T_LEN) / 4;          // denom float4 count
  const int total = 2 * QV + WV + DN;
  for (int idx = blockIdx.x * blockDim.x + threadIdx.x; idx < total;
       idx += gridDim.x * blockDim.x) {
    if (idx < QV) {
      int e4 = idx & 255;            // E/4 = 256
      int bt = idx >> 8;
      int t = bt & (T_LEN - 1);
      int b = bt >> 11;
      float4 v = reinterpret_cast<const float4*>(q1)[(t * B_SZ + b) * 256 + e4];
      ushort4 o;
      o.x = f2bf(v.x * SCALE); o.y = f2bf(v.y * SCALE);
      o.z = f2bf(v.z * SCALE); o.w = f2bf(v.w * SCALE);
      reinterpret_cast<ushort4*>(qbf)[idx] = o;
    } else if (idx < 2 * QV) {
      int d = idx - QV;
      int e4 = d & 255;
      int bt = d >> 8;
      int s = bt & (T_LEN - 1);
      int b = bt >> 11;
      float4 v = reinterpret_cast<const float4*>(kin)[(s * B_SZ + b) * 256 + e4];
      ushort4 o;
      o.x = f2bf(v.x); o.y = f2bf(v.y); o.z = f2bf(v.z); o.w = f2bf(v.w);
      reinterpret_cast<ushort4*>(kbf)[d] = o;
    } else if (idx < 2 * QV + WV) {
      int d = idx - 2 * QV;
      float4 v = reinterpret_cast<const float4*>(W)[d];
      ushort4 o;
      o.x = f2bf(v.x); o.y = f2bf(v.y); o.z = f2bf(v.z); o.w = f2bf(v.w);
      reinterpret_cast<ushort4*>(wbf)[d] = o;
    } else {
      int d = idx - 2 * QV - WV;
      float4 z; z.x = z.y = z.z = z.w = 0.f;
      reinterpret_cast<float4*>(denom)[d] = z;
    }
  }
}

// ---------------------------------------------------------------------------
// 256x256 bf16 GEMM core (C = A . B^T), 8 waves (2M x 4N), BK=64, 4 phases
// per K-tile, counted vmcnt, double-buffered 128 KB LDS, XOR-swizzled
// (chunk ^= row&7 on both stage source and ds_read — rule #21).
//
// Cross-wave invariants (all via asm-with-memory-clobber, NOT compiler
// fences — the compiler is free to pipeline around them):
//  * each phase's ds_reads drain at that phase's lgkmcnt(0), before the end
//    barrier after which another wave's DMA may overwrite the region
//    (A(kt) reads confined to p0/p1, drained at p1 — p2 DMAs A(kt+2) into
//    the same slot; B(kt) reads drain at p3 — kt+1 p0 DMAs B(kt+2) there).
//  * vmcnt(4) at p3 retires A(kt+1)+B(kt+1); A(kt+2) stays in flight.
//
// Stage ledger (per K-tile kt, slot S=kt&1):
//   p0 -> B-h0(kt+1) into slot 1-S    p1 -> B-h1(kt+1) into slot 1-S
//   p2 -> A-h0(kt+2) into slot S      p3 -> A-h1(kt+2) into slot S
// ---------------------------------------------------------------------------
#define RD(ptr, off) (*reinterpret_cast<const short8*>((ptr) + (off)))

#define STAGE(srcs, dstBase, KOFF)                                            \
  {                                                                           \
    _Pragma("unroll") for (int p_ = 0; p_ < 2; ++p_) {                        \
      unsigned short* dst_ = (dstBase) + (size_t)(p_ * 512 + wave * 64) * 8;  \
      __builtin_amdgcn_global_load_lds(                                       \
          (const __attribute__((address_space(1))) unsigned int*)             \
              ((srcs)[p_] + (KOFF)),                                          \
          (__attribute__((address_space(3))) unsigned int*)dst_, 16, 0, 0);   \
    }                                                                         \
  }

#define MFMAQ(MB, NB, AF, BF)                                                 \
  {                                                                           \
    _Pragma("unroll") for (int m_ = 0; m_ < 4; ++m_)                          \
      _Pragma("unroll") for (int n_ = 0; n_ < 2; ++n_)                        \
        _Pragma("unroll") for (int ks_ = 0; ks_ < 2; ++ks_)                   \
          acc[MB + m_][NB + n_] = __builtin_amdgcn_mfma_f32_16x16x32_bf16(    \
              AF[m_][ks_], BF[n_][ks_], acc[MB + m_][NB + n_], 0, 0, 0);      \
  }

#define LGKM0() asm volatile("s_waitcnt lgkmcnt(0)" ::: "memory")

// One K-tile, compile-time slot S.  DO_B/DO_A runtime guards; KOB/KOA are
// k-advances in SHORTS added to the precomputed staging source pointers.
#define KTILE(S, DO_B, DO_A, KOB, KOA)                                        \
  {                                                                           \
    short8 aL[4][2], aH[4][2], bb[2][2];                                      \
    /* ---- phase 0: A[m0-3] + B[n0-1] reads, stage B-h0(next) ---- */        \
    _Pragma("unroll") for (int m = 0; m < 4; ++m) {                           \
      aL[m][0] = RD(pA0, S * 16384 + m * 1024);                               \
      aL[m][1] = RD(pA1, S * 16384 + m * 1024);                               \
    }                                                                         \
    _Pragma("unroll") for (int n = 0; n < 2; ++n) {                           \
      bb[n][0] = RD(pB0, S * 16384 + n * 1024);                               \
      bb[n][1] = RD(pB1, S * 16384 + n * 1024);                               \
    }                                                                         \
    if (DO_B) STAGE(sB0, ldsB + (1 - S) * 16384, KOB);                        \
    BARRIER();                                                                \
    __builtin_amdgcn_s_setprio(1);                                            \
    MFMAQ(0, 0, aL, bb);                                                      \
    __builtin_amdgcn_s_setprio(0);                                            \
    LGKM0();                                                                  \
    BARRIER();                                                                \
    /* ---- phase 1: A[m4-7] reads, stage B-h1(next) ---- */                  \
    _Pragma("unroll") for (int m = 0; m < 4; ++m) {                           \
      aH[m][0] = RD(pA0, S * 16384 + (4 + m) * 1024);                         \
      aH[m][1] = RD(pA1, S * 16384 + (4 + m) * 1024);                         \
    }                                                                         \
    if (DO_B) STAGE(sB1, ldsB + (1 - S) * 16384 + 8192, KOB);                 \
    BARRIER();                                                                \
    __builtin_amdgcn_s_setprio(1);                                            \
    MFMAQ(4, 0, aH, bb);                                                      \
    __builtin_amdgcn_s_setprio(0);                                            \
    LGKM0();                                                                  \
    BARRIER();                                                                \
    /* ---- phase 2: B[n2-3] reads, stage A-h0(next2) ---- */                 \
    _Pragma("unroll") for (int n = 0; n < 2; ++n) {                           \
      bb[n][0] = RD(pB0, S * 16384 + (2 + n) * 1024);                         \
      bb[n][1] = RD(pB1, S * 16384 + (2 + n) * 1024);                         \
    }                                                                         \
    if (DO_A) STAGE(sA0, ldsA + S * 16384, KOA);                              \
    BARRIER();                                                                \
    __builtin_amdgcn_s_setprio(1);                                            \
    MFMAQ(0, 2, aL, bb);                                                      \
    __builtin_amdgcn_s_setprio(0);                                            \
    LGKM0();                                                                  \
    BARRIER();                                                                \
    /* ---- phase 3: stage A-h1(next2), counted vmcnt ---- */                 \
    if (DO_A) {                                                               \
      STAGE(sA1, ldsA + S * 16384 + 8192, KOA);                               \
      asm volatile("s_waitcnt vmcnt(4)" ::: "memory");                        \
    } else {                                                                  \
      asm volatile("s_waitcnt vmcnt(0)" ::: "memory");                        \
    }                                                                         \
    BARRIER();                                                                \
    __builtin_amdgcn_s_setprio(1);                                            \
    MFMAQ(4, 2, aH, bb);                                                      \
    __builtin_amdgcn_s_setprio(0);                                            \
    LGKM0();                                                                  \
    BARRIER();                                                                \
  }

__device__ __forceinline__ void gemm256(
    const unsigned short* __restrict__ A, size_t lda, int r0,
    const unsigned short* __restrict__ B, size_t ldb, int c0,
    int NKT, unsigned short* lds, f32x4 acc[8][4]) {
  const int tid = threadIdx.x;
  const int lane = tid & 63, wave = tid >> 6;
  const int lr = lane & 15, lg = lane >> 4;
  const int wr = wave >> 2, wc = wave & 3;
  unsigned short* ldsA = lds;              // [slot][half] halves of 8192 shorts
  unsigned short* ldsB = lds + 4 * 8192;

  // LDS read base pointers (swizzle baked in; (m*16)&7==0, (wc*64+n*16)&7==0)
  const unsigned short* pA0 = ldsA + wr * 8192 + lr * 64 + ((0 + lg) ^ (lr & 7)) * 8;
  const unsigned short* pA1 = ldsA + wr * 8192 + lr * 64 + ((4 + lg) ^ (lr & 7)) * 8;
  const unsigned short* pB0 = ldsB + (wc >> 1) * 8192 + ((wc & 1) * 64 + lr) * 64 +
                              ((0 + lg) ^ (lr & 7)) * 8;
  const unsigned short* pB1 = ldsB + (wc >> 1) * 8192 + ((wc & 1) * 64 + lr) * 64 +
                              ((4 + lg) ^ (lr & 7)) * 8;

  // Per-thread staging source pointers (inverse-swizzled), advance 128 sh/iter
  const unsigned short* sA0[2]; const unsigned short* sA1[2];
  const unsigned short* sB0[2]; const unsigned short* sB1[2];
#pragma unroll
  for (int p = 0; p < 2; ++p) {
    int c = p * 512 + tid, row = c >> 3, cg = (c & 7) ^ (row & 7);
    sA0[p] = A + (size_t)(r0 + row) * lda + cg * 8;
    sA1[p] = A + (size_t)(r0 + 128 + row) * lda + cg * 8;
    sB0[p] = B + (size_t)(c0 + row) * ldb + cg * 8;
    sB1[p] = B + (size_t)(c0 + 128 + row) * ldb + cg * 8;
  }

  // Prologue: kt0 {A-h0,A-h1,B-h0,B-h1}, kt1 {A-h0,A-h1}; 12 insts in flight
  STAGE(sA0, ldsA, 0);
  STAGE(sA1, ldsA + 8192, 0);
  STAGE(sB0, ldsB, 0);
  STAGE(sB1, ldsB + 8192, 0);
  STAGE(sA0, ldsA + 16384, 64);
  STAGE(sA1, ldsA + 16384 + 8192, 64);
  asm volatile("s_waitcnt vmcnt(4)" ::: "memory");  // kt0 landed, kt1-A flying
  BARRIER();

  const int nit = NKT >> 1;
  for (int it = 0; it < nit; ++it) {
    const bool notLast = (it != nit - 1);
    // even K-tile (slot 0): stage B(kt+1)@+64, A(kt+2)@+128 (shorts)
    KTILE(0, true, notLast, 64, 128);
    // odd K-tile (slot 1): stage B(kt+1)@+128, A(kt+2)@+192
    KTILE(1, notLast, notLast, 128, 192);
#pragma unroll
    for (int p = 0; p < 2; ++p) {
      sA0[p] += 128; sA1[p] += 128; sB0[p] += 128; sB1[p] += 128;
    }
  }
}

// ---------------------------------------------------------------------------
// Kernel 2: V projection. rows r = b*S+s over kbf, cols o over W rows.
// Output transposed: vT[b][o][s] (bf16), bias added.
// ---------------------------------------------------------------------------
__global__ __launch_bounds__(512, 2) void proj_kernel(
    const unsigned short* __restrict__ kbf,
    const unsigned short* __restrict__ wbf,
    const float* __restrict__ bias,
    unsigned short* __restrict__ vT) {
  __shared__ unsigned short lds[65536];
  const int lane = threadIdx.x & 63, wave = threadIdx.x >> 6;
  const int lr = lane & 15, lg = lane >> 4;
  const int wr = wave >> 2, wc = wave & 3;
  const int r0 = blockIdx.x * 256;
  const int c0 = blockIdx.y * 256;
  f32x4 acc[8][4] = {};
  gemm256(kbf, E_DIM, r0, wbf, E_DIM, c0, E_DIM / 64, lds, acc);
#pragma unroll
  for (int n = 0; n < 4; ++n) {
    int o = c0 + wc * 64 + n * 16 + lr;
    float bv = bias[o];
#pragma unroll
    for (int m = 0; m < 8; ++m) {
#pragma unroll
      for (int i = 0; i < 4; ++i) {
        int r = r0 + wr * 128 + m * 16 + lg * 4 + i;
        int b = r >> 11;            // r = b*S + s
        int s = r & (S_LEN - 1);
        vT[((size_t)b * E_DIM + o) * S_LEN + s] = f2bf(acc[m][n][i] + bv);
      }
    }
  }
}

// ---------------------------------------------------------------------------
// Kernel 3: unnormalized attention weights.
//   P[b][tl][s] = bf16( exp(q[b][t].k[b][s]) )  (no max subtraction; scores
//   ~N(0,16) -> exp finite in fp32/bf16), denom[b][t] += row partials.
// 1D grid with XCD-aware bijective swizzle; inner index = t-tile.
// ---------------------------------------------------------------------------
__global__ __launch_bounds__(512, 2) void scores_kernel(
    const unsigned short* __restrict__ qbf,
    const unsigned short* __restrict__ kbf,
    unsigned short* __restrict__ P, float* __restrict__ denom,
    int tbase, int trows, int ntx) {
  __shared__ unsigned short lds[65536];
  const int nwg = gridDim.x;              // divisible by 8
  const int per = nwg >> 3;
  const int wgid = (blockIdx.x & 7) * per + (blockIdx.x >> 3);
  const int b = wgid / (ntx * 8);
  const int rem = wgid - b * (ntx * 8);
  const int ty = rem / ntx;               // s-tile
  const int tx = rem - ty * ntx;          // t-tile (inner: shares K panel)
  const int lane = threadIdx.x & 63, wave = threadIdx.x >> 6;
  const int lr = lane & 15, lg = lane >> 4;
  const int wr = wave >> 2, wc = wave & 3;
  const int t0l = tx * 256;               // local t tile base in chunk
  const int s0 = ty * 256;
  const unsigned short* Q = qbf + (size_t)b * T_LEN * E_DIM;
  const unsigned short* K = kbf + (size_t)b * S_LEN * E_DIM;
  f32x4 acc[8][4] = {};
  gemm256(Q, E_DIM, tbase + t0l, K, E_DIM, s0, E_DIM / 64, lds, acc);
  unsigned short* outp = P + (size_t)b * trows * S_LEN;
  float* dn = denom + (size_t)b * T_LEN + tbase;
#pragma unroll
  for (int m = 0; m < 8; ++m) {
#pragma unroll
    for (int i = 0; i < 4; ++i) {
      int tl = t0l + wr * 128 + m * 16 + lg * 4 + i;
      float rp = 0.f;
#pragma unroll
      for (int n = 0; n < 4; ++n) {
        float e = __expf(acc[m][n][i]);
        rp += e;
        int s = s0 + wc * 64 + n * 16 + lr;
        outp[(size_t)tl * S_LEN + s] = f2bf(e);
      }
#pragma unroll
      for (int off = 1; off < 16; off <<= 1) rp += __shfl_xor(rp, off);
      if (lr == 0) atomicAdd(&dn[tl], rp);
    }
  }
}

// ---------------------------------------------------------------------------
// Kernel 4: out[t][b][e] = (sum_s P_u[b][t][s] * v[b][s][e]) / denom[b][t]
// (deferred normalization in the epilogue).  1D grid, XCD swizzle.
// ---------------------------------------------------------------------------
__global__ __launch_bounds__(512, 2) void pv_kernel(
    const unsigned short* __restrict__ pbf,
    const unsigned short* __restrict__ vT,
    const float* __restrict__ denom,
    float* __restrict__ out, int tbase, int trows, int ntx) {
  __shared__ unsigned short lds[65536];
  const int nwg = gridDim.x;              // divisible by 8
  const int per = nwg >> 3;
  const int wgid = (blockIdx.x & 7) * per + (blockIdx.x >> 3);
  const int b = wgid / (ntx * 4);
  const int rem = wgid - b * (ntx * 4);
  const int ey = rem / ntx;               // e-tile
  const int tx = rem - ey * ntx;          // t-tile (inner: shares vT panel)
  const int lane = threadIdx.x & 63, wave = threadIdx.x >> 6;
  const int lr = lane & 15, lg = lane >> 4;
  const int wr = wave >> 2, wc = wave & 3;
  const int tl0 = tx * 256;               // local row in chunk
  const int e0 = ey * 256;
  const unsigned short* Pp = pbf + (size_t)b * trows * S_LEN;
  const unsigned short* V = vT + (size_t)b * E_DIM * S_LEN;
  f32x4 acc[8][4] = {};
  gemm256(Pp, S_LEN, tl0, V, S_LEN, e0, S_LEN / 64, lds, acc);
  const float* dn = denom + (size_t)b * T_LEN + tbase;
#pragma unroll
  for (int m = 0; m < 8; ++m) {
#pragma unroll
    for (int i = 0; i < 4; ++i) {
      int tl = tl0 + wr * 128 + m * 16 + lg * 4 + i;
      float invd = 1.0f / dn[tl];
      int t = tbase + tl;
#pragma unroll
      for (int n = 0; n < 4; ++n) {
        int e = e0 + wc * 64 + n * 16 + lr;
        out[((size_t)t * B_SZ + b) * E_DIM + e] = acc[m][n][i] * invd;
      }
    }
  }
}

// ---------------------------------------------------------------------------
extern "C" void kernel_launch(void* const* d_in, const int* in_sizes, int n_in,
                              void* d_out, int out_size, void* d_ws, size_t ws_size,
                              hipStream_t stream) {
  const float* q1 = (const float*)d_in[0];
  const float* k = (const float*)d_in[1];
  // d_in[2] = value: unused by reference
  const float* W = (const float*)d_in[3];
  const float* bias = (const float*)d_in[4];
  float* out = (float*)d_out;

  char* ws = (char*)d_ws;
  const size_t QB = (size_t)B_SZ * T_LEN * E_DIM * 2;   // 33.5 MB each
  const size_t WBYTES = (size_t)E_DIM * E_DIM * 2;      // 2 MB
  const size_t DBYTES = (size_t)B_SZ * T_LEN * 4;       // 64 KB
  unsigned short* qbf = (unsigned short*)(ws);
  unsigned short* kbf = (unsigned short*)(ws + QB);
  unsigned short* vT = (unsigned short*)(ws + 2 * QB);
  unsigned short* wbf = (unsigned short*)(ws + 3 * QB);
  float* denom = (float*)(ws + 3 * QB + WBYTES);
  unsigned short* P = (unsigned short*)(ws + 3 * QB + WBYTES + DBYTES);
  const size_t fixed = 3 * QB + WBYTES + DBYTES;        // ~100.8 MB

  // t-chunk size (multiple of 256) for the bf16 P buffer.
  size_t avail = ws_size > fixed ? ws_size - fixed : 0;
  int tpc = (int)(avail / ((size_t)B_SZ * S_LEN * 2));
  tpc = (tpc / 256) * 256;
  if (tpc > T_LEN) tpc = T_LEN;
  if (tpc < 256) tpc = 256;  // last resort

  prep_kernel<<<dim3(2048), dim3(256), 0, stream>>>(q1, k, W, qbf, kbf, wbf,
                                                    denom);
  proj_kernel<<<dim3((B_SZ * S_LEN) / 256, E_DIM / 256), dim3(512), 0, stream>>>(
      kbf, wbf, bias, vT);

  for (int tbase = 0; tbase < T_LEN; tbase += tpc) {
    int trows = T_LEN - tbase < tpc ? T_LEN - tbase : tpc;
    int ntx = trows / 256;
    scores_kernel<<<dim3(ntx * (S_LEN / 256) * B_SZ), dim3(512), 0, stream>>>(
        qbf, kbf, P, denom, tbase, trows, ntx);
    pv_kernel<<<dim3(ntx * (E_DIM / 256) * B_SZ), dim3(512), 0, stream>>>(
        P, vT, denom, out, tbase, trows, ntx);
  }
}